// Round 19
// baseline (148.077 us; speedup 1.0000x reference)
//
#include <hip/hip_runtime.h>
#include <math.h>

#define I_N 128
#define C_N 128
#define R_N 36
#define W_N 24
#define D_N 512
#define M_N (I_N * R_N)   // 4608
#define N_N (C_N * W_N)   // 3072

typedef __attribute__((ext_vector_type(8))) short bf16x8;
typedef __attribute__((ext_vector_type(4))) float f32x4;
typedef __attribute__((ext_vector_type(8))) unsigned short u16x8;
typedef _Float16 f16x2 __attribute__((ext_vector_type(2)));
typedef __fp16 h16x2 __attribute__((ext_vector_type(2)));

__device__ inline float bf2f(unsigned short u) {
    return __uint_as_float(((unsigned int)u) << 16);
}
__device__ inline unsigned short f2bf(float f) {
    unsigned int u = __float_as_uint(f);
    u = (u + 0x7FFFu + ((u >> 16) & 1u)) >> 16;
    return (unsigned short)u;
}
__device__ inline void gload_lds16(const void* g, void* l) {
    __builtin_amdgcn_global_load_lds(
        (const __attribute__((address_space(1))) void*)g,
        (__attribute__((address_space(3))) void*)l, 16, 0, 0);
}

#if __has_builtin(__builtin_amdgcn_fdot2)
__device__ inline float fdot2f(f16x2 a, f16x2 b, float c) {
    return __builtin_amdgcn_fdot2(__builtin_bit_cast(h16x2, a),
                                  __builtin_bit_cast(h16x2, b), c, false);
}
#else
__device__ inline float fdot2f(f16x2 a, f16x2 b, float c) {
    return c + (float)a[0] * (float)b[0] + (float)a[1] * (float)b[1];
}
#endif

#if __has_builtin(__builtin_amdgcn_cvt_pkrtz)
__device__ inline f16x2 pkf16(float a, float b) {
    return __builtin_bit_cast(f16x2, __builtin_amdgcn_cvt_pkrtz(a, b));
}
#else
__device__ inline f16x2 pkf16(float a, float b) {
    f16x2 v; v[0] = (_Float16)a; v[1] = (_Float16)b; return v;
}
#endif

// ---------------------------------------------------------------------------
// Kernel 0 (fused prologue). Grid 2049 x 256 (R18 form + counter reset).
// ---------------------------------------------------------------------------
__global__ __launch_bounds__(256) void prologue_kernel(const float* __restrict__ images,
                                                       const float* __restrict__ captions,
                                                       const int* __restrict__ cap_lens,
                                                       unsigned short* __restrict__ imgbf,
                                                       unsigned short* __restrict__ capbf,
                                                       float* __restrict__ capn,
                                                       unsigned int* __restrict__ G2,
                                                       int* __restrict__ NVp,
                                                       int* __restrict__ crow_tab,
                                                       int* __restrict__ cw_tab,
                                                       int* __restrict__ counter) {
    __shared__ float tile[R_N][68];
    __shared__ float gshf[R_N][R_N];
    const int bid = blockIdx.x;
    const int tid = threadIdx.x;
    if (bid == 2048) {
        __shared__ int S_sh[C_N + 1];
        if (tid == 0) {
            int s = 0;
            for (int c = 0; c < C_N; ++c) { S_sh[c] = s; s += cap_lens[c]; }
            S_sh[C_N] = s;
            NVp[0] = s;
            counter[0] = 0;
        }
        __syncthreads();
        const int NV = S_sh[C_N];
        if (tid < C_N) {
            int base = S_sh[tid];
            int len = cap_lens[tid];
            for (int w = 0; w < len; ++w) {
                crow_tab[base + w] = tid * W_N + w;
                cw_tab[base + w] = (tid << 5) | w;
            }
        }
        for (int idx = NV + tid; idx < N_N; idx += 256) {
            crow_tab[idx] = 0;
            cw_tab[idx] = 0;
        }
        return;
    }
    if (bid < I_N) {
        const int i = bid;
        const float* img = images + (size_t)i * R_N * D_N;
        const int t1 = (tid / 12) * 3;
        const int t2 = (tid % 12) * 3;
        const bool active = tid < 144;
        float acc[3][3] = {{0.f,0.f,0.f},{0.f,0.f,0.f},{0.f,0.f,0.f}};
        for (int k0 = 0; k0 < D_N; k0 += 64) {
            for (int idx = tid; idx < R_N * 16; idx += 256) {
                int r = idx / 16, k4 = idx % 16;
                float4 v = *(const float4*)(img + (size_t)r * D_N + k0 + k4 * 4);
                *(float4*)&tile[r][k4 * 4] = v;
            }
            __syncthreads();
            if (active) {
                #pragma unroll
                for (int k = 0; k < 64; k += 4) {
                    float4 a0 = *(const float4*)&tile[t1 + 0][k];
                    float4 a1 = *(const float4*)&tile[t1 + 1][k];
                    float4 a2 = *(const float4*)&tile[t1 + 2][k];
                    float4 b0 = *(const float4*)&tile[t2 + 0][k];
                    float4 b1 = *(const float4*)&tile[t2 + 1][k];
                    float4 b2 = *(const float4*)&tile[t2 + 2][k];
                    acc[0][0] += a0.x*b0.x + a0.y*b0.y + a0.z*b0.z + a0.w*b0.w;
                    acc[0][1] += a0.x*b1.x + a0.y*b1.y + a0.z*b1.z + a0.w*b1.w;
                    acc[0][2] += a0.x*b2.x + a0.y*b2.y + a0.z*b2.z + a0.w*b2.w;
                    acc[1][0] += a1.x*b0.x + a1.y*b0.y + a1.z*b0.z + a1.w*b0.w;
                    acc[1][1] += a1.x*b1.x + a1.y*b1.y + a1.z*b1.z + a1.w*b1.w;
                    acc[1][2] += a1.x*b2.x + a1.y*b2.y + a1.z*b2.z + a1.w*b2.w;
                    acc[2][0] += a2.x*b0.x + a2.y*b0.y + a2.z*b0.z + a2.w*b0.w;
                    acc[2][1] += a2.x*b1.x + a2.y*b1.y + a2.z*b1.z + a2.w*b1.w;
                    acc[2][2] += a2.x*b2.x + a2.y*b2.y + a2.z*b2.z + a2.w*b2.w;
                }
            }
            __syncthreads();
        }
        if (active) {
            #pragma unroll
            for (int a = 0; a < 3; ++a)
                #pragma unroll
                for (int b = 0; b < 3; ++b)
                    gshf[t1 + a][t2 + b] = acc[a][b];
        }
        __syncthreads();
        unsigned int* gp = G2 + (size_t)i * (R_N * 20);
        for (int idx = tid; idx < R_N * 20; idx += 256) {
            int r = idx / 20, p = idx % 20;
            f16x2 v;
            if (p < 18) v = pkf16(gshf[r][2 * p], gshf[r][2 * p + 1]);
            else { v[0] = (_Float16)0.f; v[1] = (_Float16)0.f; }
            gp[idx] = __builtin_bit_cast(unsigned int, v);
        }
    } else if (bid < I_N + 1152) {
        int idx = (bid - I_N) * 256 + tid;
        float4 v0 = *(const float4*)(images + (size_t)idx * 8);
        float4 v1 = *(const float4*)(images + (size_t)idx * 8 + 4);
        u16x8 o;
        o[0] = f2bf(v0.x); o[1] = f2bf(v0.y); o[2] = f2bf(v0.z); o[3] = f2bf(v0.w);
        o[4] = f2bf(v1.x); o[5] = f2bf(v1.y); o[6] = f2bf(v1.z); o[7] = f2bf(v1.w);
        *(u16x8*)(imgbf + (size_t)idx * 8) = o;
    } else {
        const int crow = (bid - I_N - 1152) * 4 + (tid >> 6);
        const int lane = tid & 63;
        const float* p = captions + (size_t)crow * D_N + lane * 8;
        float4 v0 = *(const float4*)p;
        float4 v1 = *(const float4*)(p + 4);
        u16x8 o;
        o[0] = f2bf(v0.x); o[1] = f2bf(v0.y); o[2] = f2bf(v0.z); o[3] = f2bf(v0.w);
        o[4] = f2bf(v1.x); o[5] = f2bf(v1.y); o[6] = f2bf(v1.z); o[7] = f2bf(v1.w);
        *(u16x8*)(capbf + (size_t)crow * D_N + lane * 8) = o;
        float s = v0.x*v0.x + v0.y*v0.y + v0.z*v0.z + v0.w*v0.w
                + v1.x*v1.x + v1.y*v1.y + v1.z*v1.z + v1.w*v1.w;
        #pragma unroll
        for (int off = 32; off > 0; off >>= 1) s += __shfl_down(s, off);
        if (lane == 0) capn[crow] = sqrtf(s);
    }
}

// ---------------------------------------------------------------------------
// Kernel 1: attn GEMM over compacted columns (R18 form, verified).
// ---------------------------------------------------------------------------
#define BM 128
#define BN 128
#define BK 32
#define KT (D_N / BK)   // 16
#define GX (M_N / BM)   // 36
#define GY (N_N / BN)   // 24

__global__ __launch_bounds__(256, 4) void attn_gemm_kernel(const unsigned short* __restrict__ A,
                                                           const unsigned short* __restrict__ B,
                                                           const int* __restrict__ NVp,
                                                           const int* __restrict__ crow_tab,
                                                           const int* __restrict__ cw_tab,
                                                           unsigned short* __restrict__ attn) {
    __shared__ unsigned short AsBuf[2][BM * BK];
    __shared__ unsigned short BsBuf[2][BN * BK];
    const int flat = blockIdx.x;
    const int nf = (flat & 7) * (GX * GY / 8) + (flat >> 3);
    const int m0 = (nf / GY) * BM;
    const int n0 = (nf % GY) * BN;
    const int NV = NVp[0];
    if (n0 >= NV) return;
    const int tid = threadIdx.x;
    const int lane = tid & 63;
    const int wid = tid >> 6;
    const int wr = wid >> 1, wc = wid & 1;
    const int fr = lane & 15;
    const int fk = lane >> 4;

    const int srow = tid >> 2;
    const int sslot = (tid & 3) ^ (srow & 3) ^ ((srow >> 2) & 3);
    const unsigned short* srcA = A + (size_t)(m0 + srow) * D_N + sslot * 8;
    const int crow0 = crow_tab[n0 + srow];
    const int crow1 = crow_tab[n0 + srow + 64];
    const unsigned short* srcB0 = B + (size_t)crow0 * D_N + sslot * 8;
    const unsigned short* srcB1 = B + (size_t)crow1 * D_N + sslot * 8;
    const int ldst = tid * 16;
    const int rswz = (fk ^ (fr & 3) ^ ((fr >> 2) & 3)) << 4;

    f32x4 acc[4][4];
    #pragma unroll
    for (int m = 0; m < 4; ++m)
        #pragma unroll
        for (int n = 0; n < 4; ++n) acc[m][n] = (f32x4){0.f, 0.f, 0.f, 0.f};

    #define STAGE(t, buf)                                                              \
        {                                                                              \
            gload_lds16(srcA + (t) * BK, (char*)AsBuf[buf] + ldst);                    \
            gload_lds16(srcA + (size_t)64 * D_N + (t) * BK,                            \
                        (char*)AsBuf[buf] + 4096 + ldst);                              \
            gload_lds16(srcB0 + (t) * BK, (char*)BsBuf[buf] + ldst);                   \
            gload_lds16(srcB1 + (t) * BK, (char*)BsBuf[buf] + 4096 + ldst);            \
        }

    STAGE(0, 0)
    STAGE(1, 1)
    asm volatile("s_waitcnt vmcnt(4)" ::: "memory");
    __builtin_amdgcn_sched_barrier(0);
    __builtin_amdgcn_s_barrier();
    __builtin_amdgcn_sched_barrier(0);

    #pragma unroll
    for (int t = 0; t < KT; ++t) {
        const int cur = t & 1;
        const unsigned short* As = AsBuf[cur];
        const unsigned short* Bs = BsBuf[cur];
        bf16x8 af[4], bfr[4];
        #pragma unroll
        for (int m = 0; m < 4; ++m) {
            int rl = wr * 64 + m * 16 + fr;
            af[m] = *(const bf16x8*)((const char*)As + rl * 64 + rswz);
        }
        #pragma unroll
        for (int n = 0; n < 4; ++n) {
            int rl = wc * 64 + n * 16 + fr;
            bfr[n] = *(const bf16x8*)((const char*)Bs + rl * 64 + rswz);
        }
        #pragma unroll
        for (int m = 0; m < 4; ++m)
            #pragma unroll
            for (int n = 0; n < 4; ++n)
                acc[m][n] = __builtin_amdgcn_mfma_f32_16x16x32_bf16(af[m], bfr[n], acc[m][n], 0, 0, 0);
        __builtin_amdgcn_sched_barrier(0);
        __builtin_amdgcn_s_barrier();
        __builtin_amdgcn_sched_barrier(0);
        if (t + 2 < KT) STAGE(t + 2, cur)
        if (t + 1 < KT) {
            if (t + 2 < KT) {
                asm volatile("s_waitcnt vmcnt(4)" ::: "memory");
            } else {
                asm volatile("s_waitcnt vmcnt(0)" ::: "memory");
            }
            __builtin_amdgcn_sched_barrier(0);
            __builtin_amdgcn_s_barrier();
            __builtin_amdgcn_sched_barrier(0);
        }
    }
    #undef STAGE

    #pragma unroll
    for (int n = 0; n < 4; ++n) {
        int ccol = n0 + wc * 64 + n * 16 + fr;
        if (ccol < NV) {
            int cw = cw_tab[ccol];
            int c = cw >> 5, w = cw & 31;
            #pragma unroll
            for (int m = 0; m < 4; ++m) {
                #pragma unroll
                for (int j = 0; j < 4; ++j) {
                    int row = m0 + wr * 64 + m * 16 + fk * 4 + j;
                    int i = row / R_N, r = row - i * R_N;
                    attn[(((size_t)i * C_N + c) * R_N + r) * W_N + w] = f2bf(acc[m][n][j]);
                }
            }
        }
    }
}

// ---------------------------------------------------------------------------
// Kernel 2: score + fused last-block final reduction. Grid (128, 16), 192 thr.
// Score part = R13/R18 verified form. After writing scores: threadfence
// (agent fence: L2 wb+inv) + atomicAdd(counter); last block (old==2047)
// acquires and runs the 128-thread hinge reduction -> out[0].
// ---------------------------------------------------------------------------
#define CG 8
#define SCL9 12.98425537f   // 9 * log2(e)

__global__ __launch_bounds__(192) void score_kernel(const unsigned short* __restrict__ attn,
                                                    const unsigned int* __restrict__ G2,
                                                    const float* __restrict__ capn,
                                                    const int* __restrict__ cap_lens,
                                                    float* __restrict__ scores,
                                                    int* __restrict__ counter,
                                                    float* __restrict__ out) {
    __shared__ unsigned short stage[CG * R_N * W_N];
    __shared__ __align__(16) unsigned int gsh2[R_N * 20];
    __shared__ float scl_sh[CG * R_N];
    __shared__ float red[CG][W_N];
    __shared__ int len_sh[CG];
    __shared__ int lastflag;
    const int i = blockIdx.x;
    const int c0 = blockIdx.y * CG;
    const int tid = threadIdx.x;

    if (tid < CG) len_sh[tid] = cap_lens[c0 + tid];
    const unsigned short* at = attn + ((size_t)i * C_N + c0) * R_N * W_N;
    for (int ch = tid; ch < CG * R_N * W_N / 8; ch += 192)
        *(u16x8*)&stage[ch * 8] = *(const u16x8*)(at + ch * 8);
    const unsigned int* gp = G2 + (size_t)i * (R_N * 20);
    if (tid < 180) ((uint4*)gsh2)[tid] = ((const uint4*)gp)[tid];
    __syncthreads();

    for (int row = tid; row < CG * R_N; row += 192) {
        int cl = row / R_N;
        int len = len_sh[cl];
        const unsigned short* rp = &stage[row * W_N];
        u16x8 p0 = *(const u16x8*)&rp[0];
        u16x8 p1 = *(const u16x8*)&rp[8];
        u16x8 p2 = *(const u16x8*)&rp[16];
        float ss = 0.f;
        #pragma unroll
        for (int q = 0; q < 8; ++q) {
            float x0 = bf2f(p0[q]); x0 = x0 > 0.f ? x0 : 0.1f * x0; x0 = (q      < len) ? x0 : 0.f;
            float x1 = bf2f(p1[q]); x1 = x1 > 0.f ? x1 : 0.1f * x1; x1 = (q + 8  < len) ? x1 : 0.f;
            float x2 = bf2f(p2[q]); x2 = x2 > 0.f ? x2 : 0.1f * x2; x2 = (q + 16 < len) ? x2 : 0.f;
            ss += x0 * x0 + x1 * x1 + x2 * x2;
        }
        scl_sh[row] = SCL9 / (sqrtf(ss) + 1e-8f);
    }
    __syncthreads();

    {
        const int cl = tid / W_N, w = tid - cl * W_N;
        const int len = len_sh[cl];
        const bool valid = w < len;
        const unsigned short* sb = &stage[cl * R_N * W_N];
        const float* sclp = &scl_sh[cl * R_N];
        f16x2 ep[18];
        float Z = 0.f, nu = 0.f;
        float e_prev = 0.f;
        #pragma unroll
        for (int r = 0; r < R_N; ++r) {
            float raw = bf2f(sb[r * W_N + w]);
            float x = raw > 0.f ? raw : 0.1f * raw;
            float l = valid ? x * sclp[r] : 0.f;
            float e = exp2f(l);
            Z += e;
            nu += e * raw;
            if (r & 1) ep[r >> 1] = pkf16(e_prev, e);
            else e_prev = e;
        }
        float wn = 0.f;
        #pragma unroll
        for (int r2 = 0; r2 < R_N; ++r2) {
            const unsigned int* grow = &gsh2[r2 * 20];
            uint4 q0 = *(const uint4*)(grow + 0);
            uint4 q1 = *(const uint4*)(grow + 4);
            uint4 q2 = *(const uint4*)(grow + 8);
            uint4 q3 = *(const uint4*)(grow + 12);
            uint2 q4 = *(const uint2*)(grow + 16);
            unsigned int gq[18] = {q0.x, q0.y, q0.z, q0.w, q1.x, q1.y, q1.z, q1.w,
                                   q2.x, q2.y, q2.z, q2.w, q3.x, q3.y, q3.z, q3.w,
                                   q4.x, q4.y};
            float t0 = 0.f, t1 = 0.f;
            #pragma unroll
            for (int p = 0; p < 18; ++p) {
                f16x2 g = __builtin_bit_cast(f16x2, gq[p]);
                if (p & 1) t1 = fdot2f(g, ep[p], t1);
                else       t0 = fdot2f(g, ep[p], t0);
            }
            wn += (t0 + t1) * (float)ep[r2 >> 1][r2 & 1];
        }
        float iZ = 1.f / Z;
        float cn = capn[(c0 + cl) * W_N + w];
        float den = fmaxf(cn * sqrtf(fmaxf(wn, 0.f)) * iZ, 1e-8f);
        red[cl][w] = valid ? (nu * iZ) / den * 6.0f : -3.4e38f;
    }
    __syncthreads();
    if (tid < CG) {
        float se = 0.f;
        #pragma unroll
        for (int w = 0; w < W_N; ++w) se += __expf(red[tid][w] - 6.0f);
        scores[(size_t)(c0 + tid) * I_N + i] = (__logf(se) + 6.0f) / 6.0f;
    }
    __syncthreads();   // scores stores drained (vmcnt) before fence
    if (tid == 0) {
        __threadfence();                       // release: L2 wb+inv, agent scope
        int old = atomicAdd(counter, 1);
        lastflag = (old == (I_N * (C_N / CG)) - 1) ? 1 : 0;
    }
    __syncthreads();
    if (lastflag) {
        __threadfence();                       // acquire: invalidate this XCD's caches
        __shared__ float diag[C_N];
        __shared__ float redf[C_N];
        if (tid < C_N) diag[tid] = scores[tid * C_N + tid];
        __syncthreads();
        if (tid < C_N) {
            const float di = diag[tid];
            float cs = 0.f, cim = 0.f;
            for (int k = 0; k < C_N; ++k) {
                if (k == tid) continue;
                float vs = 0.2f + scores[k * C_N + tid] - di;
                float vi = 0.2f + scores[tid * C_N + k] - di;
                cs = fmaxf(cs, vs);
                cim = fmaxf(cim, vi);
            }
            redf[tid] = cs + cim;
        }
        __syncthreads();
        #pragma unroll
        for (int off = 64; off > 0; off >>= 1) {
            if (tid < off && tid + off < C_N) redf[tid] += redf[tid + off];
            __syncthreads();
        }
        if (tid == 0) out[0] = redf[0];
    }
}

// ---------------------------------------------------------------------------
extern "C" void kernel_launch(void* const* d_in, const int* in_sizes, int n_in,
                              void* d_out, int out_size, void* d_ws, size_t ws_size,
                              hipStream_t stream) {
    (void)in_sizes; (void)n_in; (void)out_size; (void)ws_size;
    const float* images = (const float*)d_in[0];
    const float* captions = (const float*)d_in[1];
    const int* cap_lens = (const int*)d_in[2];
    float* out = (float*)d_out;

    char* wsb = (char*)d_ws;
    size_t off = 0;
    auto alloc = [&](size_t bytes) -> char* {
        char* p = wsb + off;
        off += (bytes + 255) & ~(size_t)255;
        return p;
    };
    unsigned short* imgbf = (unsigned short*)alloc((size_t)M_N * D_N * 2);
    unsigned short* capbf = (unsigned short*)alloc((size_t)N_N * D_N * 2);
    unsigned int* G2 = (unsigned int*)alloc((size_t)I_N * R_N * 20 * 4);
    float* capn = (float*)alloc((size_t)C_N * W_N * 4);
    float* scores = (float*)alloc((size_t)C_N * I_N * 4);
    int* NVp = (int*)alloc(256);
    int* crow_tab = (int*)alloc((size_t)N_N * 4);
    int* cw_tab = (int*)alloc((size_t)N_N * 4);
    int* counter = (int*)alloc(256);
    unsigned short* attn = (unsigned short*)alloc((size_t)I_N * C_N * R_N * W_N * 2);

    prologue_kernel<<<2049, 256, 0, stream>>>(images, captions, cap_lens,
                                              imgbf, capbf, capn, G2,
                                              NVp, crow_tab, cw_tab, counter);
    attn_gemm_kernel<<<GX * GY, 256, 0, stream>>>(imgbf, capbf, NVp, crow_tab, cw_tab, attn);
    score_kernel<<<dim3(I_N, C_N / CG), 192, 0, stream>>>(attn, G2, capn, cap_lens,
                                                          scores, counter, out);
}

// Round 20
// 111.885 us; speedup vs baseline: 1.3235x; 1.3235x over previous
//
#include <hip/hip_runtime.h>
#include <math.h>

#define I_N 128
#define C_N 128
#define R_N 36
#define W_N 24
#define D_N 512
#define M_N (I_N * R_N)   // 4608
#define N_N (C_N * W_N)   // 3072

typedef __attribute__((ext_vector_type(8))) short bf16x8;
typedef __attribute__((ext_vector_type(4))) float f32x4;
typedef __attribute__((ext_vector_type(8))) unsigned short u16x8;
typedef _Float16 f16x2 __attribute__((ext_vector_type(2)));
typedef __fp16 h16x2 __attribute__((ext_vector_type(2)));

__device__ inline float bf2f(unsigned short u) {
    return __uint_as_float(((unsigned int)u) << 16);
}
__device__ inline unsigned short f2bf(float f) {
    unsigned int u = __float_as_uint(f);
    u = (u + 0x7FFFu + ((u >> 16) & 1u)) >> 16;
    return (unsigned short)u;
}
__device__ inline void gload_lds16(const void* g, void* l) {
    __builtin_amdgcn_global_load_lds(
        (const __attribute__((address_space(1))) void*)g,
        (__attribute__((address_space(3))) void*)l, 16, 0, 0);
}

#if __has_builtin(__builtin_amdgcn_fdot2)
__device__ inline float fdot2f(f16x2 a, f16x2 b, float c) {
    return __builtin_amdgcn_fdot2(__builtin_bit_cast(h16x2, a),
                                  __builtin_bit_cast(h16x2, b), c, false);
}
#else
__device__ inline float fdot2f(f16x2 a, f16x2 b, float c) {
    return c + (float)a[0] * (float)b[0] + (float)a[1] * (float)b[1];
}
#endif

#if __has_builtin(__builtin_amdgcn_cvt_pkrtz)
__device__ inline f16x2 pkf16(float a, float b) {
    return __builtin_bit_cast(f16x2, __builtin_amdgcn_cvt_pkrtz(a, b));
}
#else
__device__ inline f16x2 pkf16(float a, float b) {
    f16x2 v; v[0] = (_Float16)a; v[1] = (_Float16)b; return v;
}
#endif

// ---------------------------------------------------------------------------
// Kernel 0 (fused prologue). Grid 2049 x 256:
//   blocks [0,128):    per-image Gram -> packed f16x2, row stride 20 u32
//   blocks [128,1280): image fp32->bf16 convert
//   blocks [1280,2048): caption fp32->bf16 convert + caption L2 norms
//   block  2048:       cap_lens scan + compaction tables (crow/cw/NV)
// ---------------------------------------------------------------------------
__global__ __launch_bounds__(256) void prologue_kernel(const float* __restrict__ images,
                                                       const float* __restrict__ captions,
                                                       const int* __restrict__ cap_lens,
                                                       unsigned short* __restrict__ imgbf,
                                                       unsigned short* __restrict__ capbf,
                                                       float* __restrict__ capn,
                                                       unsigned int* __restrict__ G2,
                                                       int* __restrict__ NVp,
                                                       int* __restrict__ crow_tab,
                                                       int* __restrict__ cw_tab) {
    __shared__ float tile[R_N][68];
    __shared__ float gshf[R_N][R_N];
    const int bid = blockIdx.x;
    const int tid = threadIdx.x;
    if (bid == 2048) {
        __shared__ int S_sh[C_N + 1];
        if (tid == 0) {
            int s = 0;
            for (int c = 0; c < C_N; ++c) { S_sh[c] = s; s += cap_lens[c]; }
            S_sh[C_N] = s;
            NVp[0] = s;
        }
        __syncthreads();
        const int NV = S_sh[C_N];
        if (tid < C_N) {
            int base = S_sh[tid];
            int len = cap_lens[tid];
            for (int w = 0; w < len; ++w) {
                crow_tab[base + w] = tid * W_N + w;
                cw_tab[base + w] = (tid << 5) | w;
            }
        }
        for (int idx = NV + tid; idx < N_N; idx += 256) {
            crow_tab[idx] = 0;
            cw_tab[idx] = 0;
        }
        return;
    }
    if (bid < I_N) {
        const int i = bid;
        const float* img = images + (size_t)i * R_N * D_N;
        const int t1 = (tid / 12) * 3;
        const int t2 = (tid % 12) * 3;
        const bool active = tid < 144;
        float acc[3][3] = {{0.f,0.f,0.f},{0.f,0.f,0.f},{0.f,0.f,0.f}};
        for (int k0 = 0; k0 < D_N; k0 += 64) {
            for (int idx = tid; idx < R_N * 16; idx += 256) {
                int r = idx / 16, k4 = idx % 16;
                float4 v = *(const float4*)(img + (size_t)r * D_N + k0 + k4 * 4);
                *(float4*)&tile[r][k4 * 4] = v;
            }
            __syncthreads();
            if (active) {
                #pragma unroll
                for (int k = 0; k < 64; k += 4) {
                    float4 a0 = *(const float4*)&tile[t1 + 0][k];
                    float4 a1 = *(const float4*)&tile[t1 + 1][k];
                    float4 a2 = *(const float4*)&tile[t1 + 2][k];
                    float4 b0 = *(const float4*)&tile[t2 + 0][k];
                    float4 b1 = *(const float4*)&tile[t2 + 1][k];
                    float4 b2 = *(const float4*)&tile[t2 + 2][k];
                    acc[0][0] += a0.x*b0.x + a0.y*b0.y + a0.z*b0.z + a0.w*b0.w;
                    acc[0][1] += a0.x*b1.x + a0.y*b1.y + a0.z*b1.z + a0.w*b1.w;
                    acc[0][2] += a0.x*b2.x + a0.y*b2.y + a0.z*b2.z + a0.w*b2.w;
                    acc[1][0] += a1.x*b0.x + a1.y*b0.y + a1.z*b0.z + a1.w*b0.w;
                    acc[1][1] += a1.x*b1.x + a1.y*b1.y + a1.z*b1.z + a1.w*b1.w;
                    acc[1][2] += a1.x*b2.x + a1.y*b2.y + a1.z*b2.z + a1.w*b2.w;
                    acc[2][0] += a2.x*b0.x + a2.y*b0.y + a2.z*b0.z + a2.w*b0.w;
                    acc[2][1] += a2.x*b1.x + a2.y*b1.y + a2.z*b1.z + a2.w*b1.w;
                    acc[2][2] += a2.x*b2.x + a2.y*b2.y + a2.z*b2.z + a2.w*b2.w;
                }
            }
            __syncthreads();
        }
        if (active) {
            #pragma unroll
            for (int a = 0; a < 3; ++a)
                #pragma unroll
                for (int b = 0; b < 3; ++b)
                    gshf[t1 + a][t2 + b] = acc[a][b];
        }
        __syncthreads();
        unsigned int* gp = G2 + (size_t)i * (R_N * 20);
        for (int idx = tid; idx < R_N * 20; idx += 256) {
            int r = idx / 20, p = idx % 20;
            f16x2 v;
            if (p < 18) v = pkf16(gshf[r][2 * p], gshf[r][2 * p + 1]);
            else { v[0] = (_Float16)0.f; v[1] = (_Float16)0.f; }
            gp[idx] = __builtin_bit_cast(unsigned int, v);
        }
    } else if (bid < I_N + 1152) {
        int idx = (bid - I_N) * 256 + tid;
        float4 v0 = *(const float4*)(images + (size_t)idx * 8);
        float4 v1 = *(const float4*)(images + (size_t)idx * 8 + 4);
        u16x8 o;
        o[0] = f2bf(v0.x); o[1] = f2bf(v0.y); o[2] = f2bf(v0.z); o[3] = f2bf(v0.w);
        o[4] = f2bf(v1.x); o[5] = f2bf(v1.y); o[6] = f2bf(v1.z); o[7] = f2bf(v1.w);
        *(u16x8*)(imgbf + (size_t)idx * 8) = o;
    } else {
        const int crow = (bid - I_N - 1152) * 4 + (tid >> 6);
        const int lane = tid & 63;
        const float* p = captions + (size_t)crow * D_N + lane * 8;
        float4 v0 = *(const float4*)p;
        float4 v1 = *(const float4*)(p + 4);
        u16x8 o;
        o[0] = f2bf(v0.x); o[1] = f2bf(v0.y); o[2] = f2bf(v0.z); o[3] = f2bf(v0.w);
        o[4] = f2bf(v1.x); o[5] = f2bf(v1.y); o[6] = f2bf(v1.z); o[7] = f2bf(v1.w);
        *(u16x8*)(capbf + (size_t)crow * D_N + lane * 8) = o;
        float s = v0.x*v0.x + v0.y*v0.y + v0.z*v0.z + v0.w*v0.w
                + v1.x*v1.x + v1.y*v1.y + v1.z*v1.z + v1.w*v1.w;
        #pragma unroll
        for (int off = 32; off > 0; off >>= 1) s += __shfl_down(s, off);
        if (lane == 0) capn[crow] = sqrtf(s);
    }
}

// ---------------------------------------------------------------------------
// Kernel 1: attn GEMM over COMPACTED caption-word columns (R18 verified form).
// 2-barrier K-loop, counted vmcnt(4), row-bit-folding swizzle, 4 blocks/CU.
// ---------------------------------------------------------------------------
#define BM 128
#define BN 128
#define BK 32
#define KT (D_N / BK)   // 16
#define GX (M_N / BM)   // 36
#define GY (N_N / BN)   // 24

__global__ __launch_bounds__(256, 4) void attn_gemm_kernel(const unsigned short* __restrict__ A,
                                                           const unsigned short* __restrict__ B,
                                                           const int* __restrict__ NVp,
                                                           const int* __restrict__ crow_tab,
                                                           const int* __restrict__ cw_tab,
                                                           unsigned short* __restrict__ attn) {
    __shared__ unsigned short AsBuf[2][BM * BK];
    __shared__ unsigned short BsBuf[2][BN * BK];
    const int flat = blockIdx.x;
    const int nf = (flat & 7) * (GX * GY / 8) + (flat >> 3);
    const int m0 = (nf / GY) * BM;
    const int n0 = (nf % GY) * BN;
    const int NV = NVp[0];
    if (n0 >= NV) return;
    const int tid = threadIdx.x;
    const int lane = tid & 63;
    const int wid = tid >> 6;
    const int wr = wid >> 1, wc = wid & 1;
    const int fr = lane & 15;
    const int fk = lane >> 4;

    const int srow = tid >> 2;
    const int sslot = (tid & 3) ^ (srow & 3) ^ ((srow >> 2) & 3);
    const unsigned short* srcA = A + (size_t)(m0 + srow) * D_N + sslot * 8;
    const int crow0 = crow_tab[n0 + srow];
    const int crow1 = crow_tab[n0 + srow + 64];
    const unsigned short* srcB0 = B + (size_t)crow0 * D_N + sslot * 8;
    const unsigned short* srcB1 = B + (size_t)crow1 * D_N + sslot * 8;
    const int ldst = tid * 16;
    const int rswz = (fk ^ (fr & 3) ^ ((fr >> 2) & 3)) << 4;

    f32x4 acc[4][4];
    #pragma unroll
    for (int m = 0; m < 4; ++m)
        #pragma unroll
        for (int n = 0; n < 4; ++n) acc[m][n] = (f32x4){0.f, 0.f, 0.f, 0.f};

    #define STAGE(t, buf)                                                              \
        {                                                                              \
            gload_lds16(srcA + (t) * BK, (char*)AsBuf[buf] + ldst);                    \
            gload_lds16(srcA + (size_t)64 * D_N + (t) * BK,                            \
                        (char*)AsBuf[buf] + 4096 + ldst);                              \
            gload_lds16(srcB0 + (t) * BK, (char*)BsBuf[buf] + ldst);                   \
            gload_lds16(srcB1 + (t) * BK, (char*)BsBuf[buf] + 4096 + ldst);            \
        }

    STAGE(0, 0)
    STAGE(1, 1)
    asm volatile("s_waitcnt vmcnt(4)" ::: "memory");
    __builtin_amdgcn_sched_barrier(0);
    __builtin_amdgcn_s_barrier();
    __builtin_amdgcn_sched_barrier(0);

    #pragma unroll
    for (int t = 0; t < KT; ++t) {
        const int cur = t & 1;
        const unsigned short* As = AsBuf[cur];
        const unsigned short* Bs = BsBuf[cur];
        bf16x8 af[4], bfr[4];
        #pragma unroll
        for (int m = 0; m < 4; ++m) {
            int rl = wr * 64 + m * 16 + fr;
            af[m] = *(const bf16x8*)((const char*)As + rl * 64 + rswz);
        }
        #pragma unroll
        for (int n = 0; n < 4; ++n) {
            int rl = wc * 64 + n * 16 + fr;
            bfr[n] = *(const bf16x8*)((const char*)Bs + rl * 64 + rswz);
        }
        #pragma unroll
        for (int m = 0; m < 4; ++m)
            #pragma unroll
            for (int n = 0; n < 4; ++n)
                acc[m][n] = __builtin_amdgcn_mfma_f32_16x16x32_bf16(af[m], bfr[n], acc[m][n], 0, 0, 0);
        __builtin_amdgcn_sched_barrier(0);
        __builtin_amdgcn_s_barrier();
        __builtin_amdgcn_sched_barrier(0);
        if (t + 2 < KT) STAGE(t + 2, cur)
        if (t + 1 < KT) {
            if (t + 2 < KT) {
                asm volatile("s_waitcnt vmcnt(4)" ::: "memory");
            } else {
                asm volatile("s_waitcnt vmcnt(0)" ::: "memory");
            }
            __builtin_amdgcn_sched_barrier(0);
            __builtin_amdgcn_s_barrier();
            __builtin_amdgcn_sched_barrier(0);
        }
    }
    #undef STAGE

    #pragma unroll
    for (int n = 0; n < 4; ++n) {
        int ccol = n0 + wc * 64 + n * 16 + fr;
        if (ccol < NV) {
            int cw = cw_tab[ccol];
            int c = cw >> 5, w = cw & 31;
            #pragma unroll
            for (int m = 0; m < 4; ++m) {
                #pragma unroll
                for (int j = 0; j < 4; ++j) {
                    int row = m0 + wr * 64 + m * 16 + fk * 4 + j;
                    int i = row / R_N, r = row - i * R_N;
                    attn[(((size_t)i * C_N + c) * R_N + r) * W_N + w] = f2bf(acc[m][n][j]);
                }
            }
        }
    }
}

// ---------------------------------------------------------------------------
// Kernel 2: score (R13/R18 verified form — CG=8, one column/thread).
// ---------------------------------------------------------------------------
#define CG 8
#define SCL9 12.98425537f   // 9 * log2(e)

__global__ __launch_bounds__(192) void score_kernel(const unsigned short* __restrict__ attn,
                                                    const unsigned int* __restrict__ G2,
                                                    const float* __restrict__ capn,
                                                    const int* __restrict__ cap_lens,
                                                    float* __restrict__ scores) {
    __shared__ unsigned short stage[CG * R_N * W_N];
    __shared__ __align__(16) unsigned int gsh2[R_N * 20];
    __shared__ float scl_sh[CG * R_N];
    __shared__ float red[CG][W_N];
    __shared__ int len_sh[CG];
    const int i = blockIdx.x;
    const int c0 = blockIdx.y * CG;
    const int tid = threadIdx.x;

    if (tid < CG) len_sh[tid] = cap_lens[c0 + tid];
    const unsigned short* at = attn + ((size_t)i * C_N + c0) * R_N * W_N;
    for (int ch = tid; ch < CG * R_N * W_N / 8; ch += 192)
        *(u16x8*)&stage[ch * 8] = *(const u16x8*)(at + ch * 8);
    const unsigned int* gp = G2 + (size_t)i * (R_N * 20);
    if (tid < 180) ((uint4*)gsh2)[tid] = ((const uint4*)gp)[tid];
    __syncthreads();

    for (int row = tid; row < CG * R_N; row += 192) {
        int cl = row / R_N;
        int len = len_sh[cl];
        const unsigned short* rp = &stage[row * W_N];
        u16x8 p0 = *(const u16x8*)&rp[0];
        u16x8 p1 = *(const u16x8*)&rp[8];
        u16x8 p2 = *(const u16x8*)&rp[16];
        float ss = 0.f;
        #pragma unroll
        for (int q = 0; q < 8; ++q) {
            float x0 = bf2f(p0[q]); x0 = x0 > 0.f ? x0 : 0.1f * x0; x0 = (q      < len) ? x0 : 0.f;
            float x1 = bf2f(p1[q]); x1 = x1 > 0.f ? x1 : 0.1f * x1; x1 = (q + 8  < len) ? x1 : 0.f;
            float x2 = bf2f(p2[q]); x2 = x2 > 0.f ? x2 : 0.1f * x2; x2 = (q + 16 < len) ? x2 : 0.f;
            ss += x0 * x0 + x1 * x1 + x2 * x2;
        }
        scl_sh[row] = SCL9 / (sqrtf(ss) + 1e-8f);
    }
    __syncthreads();

    {
        const int cl = tid / W_N, w = tid - cl * W_N;
        const int len = len_sh[cl];
        const bool valid = w < len;
        const unsigned short* sb = &stage[cl * R_N * W_N];
        const float* sclp = &scl_sh[cl * R_N];
        f16x2 ep[18];
        float Z = 0.f, nu = 0.f;
        float e_prev = 0.f;
        #pragma unroll
        for (int r = 0; r < R_N; ++r) {
            float raw = bf2f(sb[r * W_N + w]);
            float x = raw > 0.f ? raw : 0.1f * raw;
            float l = valid ? x * sclp[r] : 0.f;
            float e = exp2f(l);
            Z += e;
            nu += e * raw;
            if (r & 1) ep[r >> 1] = pkf16(e_prev, e);
            else e_prev = e;
        }
        float wn = 0.f;
        #pragma unroll
        for (int r2 = 0; r2 < R_N; ++r2) {
            const unsigned int* grow = &gsh2[r2 * 20];
            uint4 q0 = *(const uint4*)(grow + 0);
            uint4 q1 = *(const uint4*)(grow + 4);
            uint4 q2 = *(const uint4*)(grow + 8);
            uint4 q3 = *(const uint4*)(grow + 12);
            uint2 q4 = *(const uint2*)(grow + 16);
            unsigned int gq[18] = {q0.x, q0.y, q0.z, q0.w, q1.x, q1.y, q1.z, q1.w,
                                   q2.x, q2.y, q2.z, q2.w, q3.x, q3.y, q3.z, q3.w,
                                   q4.x, q4.y};
            float t0 = 0.f, t1 = 0.f;
            #pragma unroll
            for (int p = 0; p < 18; ++p) {
                f16x2 g = __builtin_bit_cast(f16x2, gq[p]);
                if (p & 1) t1 = fdot2f(g, ep[p], t1);
                else       t0 = fdot2f(g, ep[p], t0);
            }
            wn += (t0 + t1) * (float)ep[r2 >> 1][r2 & 1];
        }
        float iZ = 1.f / Z;
        float cn = capn[(c0 + cl) * W_N + w];
        float den = fmaxf(cn * sqrtf(fmaxf(wn, 0.f)) * iZ, 1e-8f);
        red[cl][w] = valid ? (nu * iZ) / den * 6.0f : -3.4e38f;
    }
    __syncthreads();
    if (tid < CG) {
        float se = 0.f;
        #pragma unroll
        for (int w = 0; w < W_N; ++w) se += __expf(red[tid][w] - 6.0f);
        scores[(size_t)(c0 + tid) * I_N + i] = (__logf(se) + 6.0f) / 6.0f;
    }
}

// ---------------------------------------------------------------------------
// Kernel 3: final hinge loss. 1 block x 128 threads.
// ---------------------------------------------------------------------------
__global__ __launch_bounds__(128) void final_kernel(const float* __restrict__ scores,
                                                    float* __restrict__ out) {
    __shared__ float diag[C_N];
    __shared__ float red[C_N];
    const int t = threadIdx.x;
    diag[t] = scores[t * C_N + t];
    __syncthreads();
    const float di = diag[t];
    float cs = 0.f, cim = 0.f;
    for (int k = 0; k < C_N; ++k) {
        if (k == t) continue;
        float vs = 0.2f + scores[k * C_N + t] - di;
        float vi = 0.2f + scores[t * C_N + k] - di;
        cs = fmaxf(cs, vs);
        cim = fmaxf(cim, vi);
    }
    red[t] = cs + cim;
    __syncthreads();
    #pragma unroll
    for (int off = 64; off > 0; off >>= 1) {
        if (t < off) red[t] += red[t + off];
        __syncthreads();
    }
    if (t == 0) out[0] = red[0];
}

// ---------------------------------------------------------------------------
extern "C" void kernel_launch(void* const* d_in, const int* in_sizes, int n_in,
                              void* d_out, int out_size, void* d_ws, size_t ws_size,
                              hipStream_t stream) {
    (void)in_sizes; (void)n_in; (void)out_size; (void)ws_size;
    const float* images = (const float*)d_in[0];
    const float* captions = (const float*)d_in[1];
    const int* cap_lens = (const int*)d_in[2];
    float* out = (float*)d_out;

    char* wsb = (char*)d_ws;
    size_t off = 0;
    auto alloc = [&](size_t bytes) -> char* {
        char* p = wsb + off;
        off += (bytes + 255) & ~(size_t)255;
        return p;
    };
    unsigned short* imgbf = (unsigned short*)alloc((size_t)M_N * D_N * 2);
    unsigned short* capbf = (unsigned short*)alloc((size_t)N_N * D_N * 2);
    unsigned int* G2 = (unsigned int*)alloc((size_t)I_N * R_N * 20 * 4);
    float* capn = (float*)alloc((size_t)C_N * W_N * 4);
    float* scores = (float*)alloc((size_t)C_N * I_N * 4);
    int* NVp = (int*)alloc(256);
    int* crow_tab = (int*)alloc((size_t)N_N * 4);
    int* cw_tab = (int*)alloc((size_t)N_N * 4);
    unsigned short* attn = (unsigned short*)alloc((size_t)I_N * C_N * R_N * W_N * 2);

    prologue_kernel<<<2049, 256, 0, stream>>>(images, captions, cap_lens,
                                              imgbf, capbf, capn, G2,
                                              NVp, crow_tab, cw_tab);
    attn_gemm_kernel<<<GX * GY, 256, 0, stream>>>(imgbf, capbf, NVp, crow_tab, cw_tab, attn);
    score_kernel<<<dim3(I_N, C_N / CG), 192, 0, stream>>>(attn, G2, capn, cap_lens, scores);
    final_kernel<<<1, 128, 0, stream>>>(scores, out);
}

// Round 22
// 111.772 us; speedup vs baseline: 1.3248x; 1.0010x over previous
//
#include <hip/hip_runtime.h>
#include <math.h>

#define I_N 128
#define C_N 128
#define R_N 36
#define W_N 24
#define D_N 512
#define M_N (I_N * R_N)   // 4608
#define N_N (C_N * W_N)   // 3072

typedef __attribute__((ext_vector_type(8))) short bf16x8;
typedef __attribute__((ext_vector_type(4))) float f32x4;
typedef __attribute__((ext_vector_type(8))) unsigned short u16x8;
typedef _Float16 f16x2 __attribute__((ext_vector_type(2)));
typedef __fp16 h16x2 __attribute__((ext_vector_type(2)));

__device__ inline float bf2f(unsigned short u) {
    return __uint_as_float(((unsigned int)u) << 16);
}
__device__ inline unsigned short f2bf(float f) {
    unsigned int u = __float_as_uint(f);
    u = (u + 0x7FFFu + ((u >> 16) & 1u)) >> 16;
    return (unsigned short)u;
}
__device__ inline void gload_lds16(const void* g, void* l) {
    __builtin_amdgcn_global_load_lds(
        (const __attribute__((address_space(1))) void*)g,
        (__attribute__((address_space(3))) void*)l, 16, 0, 0);
}

#if __has_builtin(__builtin_amdgcn_fdot2)
__device__ inline float fdot2f(f16x2 a, f16x2 b, float c) {
    return __builtin_amdgcn_fdot2(__builtin_bit_cast(h16x2, a),
                                  __builtin_bit_cast(h16x2, b), c, false);
}
#else
__device__ inline float fdot2f(f16x2 a, f16x2 b, float c) {
    return c + (float)a[0] * (float)b[0] + (float)a[1] * (float)b[1];
}
#endif

#if __has_builtin(__builtin_amdgcn_cvt_pkrtz)
__device__ inline f16x2 pkf16(float a, float b) {
    return __builtin_bit_cast(f16x2, __builtin_amdgcn_cvt_pkrtz(a, b));
}
#else
__device__ inline f16x2 pkf16(float a, float b) {
    f16x2 v; v[0] = (_Float16)a; v[1] = (_Float16)b; return v;
}
#endif

// ---------------------------------------------------------------------------
// Kernel 0 (fused prologue). Grid 2049 x 256:
//   blocks [0,128):    per-image Gram -> packed f16x2, row stride 20 u32
//   blocks [128,1280): image fp32->bf16 convert
//   blocks [1280,2048): caption fp32->bf16 convert + caption L2 norms
//   block  2048:       cap_lens scan + compaction tables (crow/cw/NV)
// ---------------------------------------------------------------------------
__global__ __launch_bounds__(256) void prologue_kernel(const float* __restrict__ images,
                                                       const float* __restrict__ captions,
                                                       const int* __restrict__ cap_lens,
                                                       unsigned short* __restrict__ imgbf,
                                                       unsigned short* __restrict__ capbf,
                                                       float* __restrict__ capn,
                                                       unsigned int* __restrict__ G2,
                                                       int* __restrict__ NVp,
                                                       int* __restrict__ crow_tab,
                                                       int* __restrict__ cw_tab) {
    __shared__ float tile[R_N][68];
    __shared__ float gshf[R_N][R_N];
    const int bid = blockIdx.x;
    const int tid = threadIdx.x;
    if (bid == 2048) {
        __shared__ int S_sh[C_N + 1];
        if (tid == 0) {
            int s = 0;
            for (int c = 0; c < C_N; ++c) { S_sh[c] = s; s += cap_lens[c]; }
            S_sh[C_N] = s;
            NVp[0] = s;
        }
        __syncthreads();
        const int NV = S_sh[C_N];
        if (tid < C_N) {
            int base = S_sh[tid];
            int len = cap_lens[tid];
            for (int w = 0; w < len; ++w) {
                crow_tab[base + w] = tid * W_N + w;
                cw_tab[base + w] = (tid << 5) | w;
            }
        }
        for (int idx = NV + tid; idx < N_N; idx += 256) {
            crow_tab[idx] = 0;
            cw_tab[idx] = 0;
        }
        return;
    }
    if (bid < I_N) {
        const int i = bid;
        const float* img = images + (size_t)i * R_N * D_N;
        const int t1 = (tid / 12) * 3;
        const int t2 = (tid % 12) * 3;
        const bool active = tid < 144;
        float acc[3][3] = {{0.f,0.f,0.f},{0.f,0.f,0.f},{0.f,0.f,0.f}};
        for (int k0 = 0; k0 < D_N; k0 += 64) {
            for (int idx = tid; idx < R_N * 16; idx += 256) {
                int r = idx / 16, k4 = idx % 16;
                float4 v = *(const float4*)(img + (size_t)r * D_N + k0 + k4 * 4);
                *(float4*)&tile[r][k4 * 4] = v;
            }
            __syncthreads();
            if (active) {
                #pragma unroll
                for (int k = 0; k < 64; k += 4) {
                    float4 a0 = *(const float4*)&tile[t1 + 0][k];
                    float4 a1 = *(const float4*)&tile[t1 + 1][k];
                    float4 a2 = *(const float4*)&tile[t1 + 2][k];
                    float4 b0 = *(const float4*)&tile[t2 + 0][k];
                    float4 b1 = *(const float4*)&tile[t2 + 1][k];
                    float4 b2 = *(const float4*)&tile[t2 + 2][k];
                    acc[0][0] += a0.x*b0.x + a0.y*b0.y + a0.z*b0.z + a0.w*b0.w;
                    acc[0][1] += a0.x*b1.x + a0.y*b1.y + a0.z*b1.z + a0.w*b1.w;
                    acc[0][2] += a0.x*b2.x + a0.y*b2.y + a0.z*b2.z + a0.w*b2.w;
                    acc[1][0] += a1.x*b0.x + a1.y*b0.y + a1.z*b0.z + a1.w*b0.w;
                    acc[1][1] += a1.x*b1.x + a1.y*b1.y + a1.z*b1.z + a1.w*b1.w;
                    acc[1][2] += a1.x*b2.x + a1.y*b2.y + a1.z*b2.z + a1.w*b2.w;
                    acc[2][0] += a2.x*b0.x + a2.y*b0.y + a2.z*b0.z + a2.w*b0.w;
                    acc[2][1] += a2.x*b1.x + a2.y*b1.y + a2.z*b1.z + a2.w*b1.w;
                    acc[2][2] += a2.x*b2.x + a2.y*b2.y + a2.z*b2.z + a2.w*b2.w;
                }
            }
            __syncthreads();
        }
        if (active) {
            #pragma unroll
            for (int a = 0; a < 3; ++a)
                #pragma unroll
                for (int b = 0; b < 3; ++b)
                    gshf[t1 + a][t2 + b] = acc[a][b];
        }
        __syncthreads();
        unsigned int* gp = G2 + (size_t)i * (R_N * 20);
        for (int idx = tid; idx < R_N * 20; idx += 256) {
            int r = idx / 20, p = idx % 20;
            f16x2 v;
            if (p < 18) v = pkf16(gshf[r][2 * p], gshf[r][2 * p + 1]);
            else { v[0] = (_Float16)0.f; v[1] = (_Float16)0.f; }
            gp[idx] = __builtin_bit_cast(unsigned int, v);
        }
    } else if (bid < I_N + 1152) {
        int idx = (bid - I_N) * 256 + tid;
        float4 v0 = *(const float4*)(images + (size_t)idx * 8);
        float4 v1 = *(const float4*)(images + (size_t)idx * 8 + 4);
        u16x8 o;
        o[0] = f2bf(v0.x); o[1] = f2bf(v0.y); o[2] = f2bf(v0.z); o[3] = f2bf(v0.w);
        o[4] = f2bf(v1.x); o[5] = f2bf(v1.y); o[6] = f2bf(v1.z); o[7] = f2bf(v1.w);
        *(u16x8*)(imgbf + (size_t)idx * 8) = o;
    } else {
        const int crow = (bid - I_N - 1152) * 4 + (tid >> 6);
        const int lane = tid & 63;
        const float* p = captions + (size_t)crow * D_N + lane * 8;
        float4 v0 = *(const float4*)p;
        float4 v1 = *(const float4*)(p + 4);
        u16x8 o;
        o[0] = f2bf(v0.x); o[1] = f2bf(v0.y); o[2] = f2bf(v0.z); o[3] = f2bf(v0.w);
        o[4] = f2bf(v1.x); o[5] = f2bf(v1.y); o[6] = f2bf(v1.z); o[7] = f2bf(v1.w);
        *(u16x8*)(capbf + (size_t)crow * D_N + lane * 8) = o;
        float s = v0.x*v0.x + v0.y*v0.y + v0.z*v0.z + v0.w*v0.w
                + v1.x*v1.x + v1.y*v1.y + v1.z*v1.z + v1.w*v1.w;
        #pragma unroll
        for (int off = 32; off > 0; off >>= 1) s += __shfl_down(s, off);
        if (lane == 0) capn[crow] = sqrtf(s);
    }
}

// ---------------------------------------------------------------------------
// Kernel 1: attn GEMM over COMPACTED caption-word columns (R18/R20 verified).
// 2-barrier K-loop, counted vmcnt(4), row-bit-folding swizzle, 4 blocks/CU.
// ---------------------------------------------------------------------------
#define BM 128
#define BN 128
#define BK 32
#define KT (D_N / BK)   // 16
#define GX (M_N / BM)   // 36
#define GY (N_N / BN)   // 24

__global__ __launch_bounds__(256, 4) void attn_gemm_kernel(const unsigned short* __restrict__ A,
                                                           const unsigned short* __restrict__ B,
                                                           const int* __restrict__ NVp,
                                                           const int* __restrict__ crow_tab,
                                                           const int* __restrict__ cw_tab,
                                                           unsigned short* __restrict__ attn) {
    __shared__ unsigned short AsBuf[2][BM * BK];
    __shared__ unsigned short BsBuf[2][BN * BK];
    const int flat = blockIdx.x;
    const int nf = (flat & 7) * (GX * GY / 8) + (flat >> 3);
    const int m0 = (nf / GY) * BM;
    const int n0 = (nf % GY) * BN;
    const int NV = NVp[0];
    if (n0 >= NV) return;
    const int tid = threadIdx.x;
    const int lane = tid & 63;
    const int wid = tid >> 6;
    const int wr = wid >> 1, wc = wid & 1;
    const int fr = lane & 15;
    const int fk = lane >> 4;

    const int srow = tid >> 2;
    const int sslot = (tid & 3) ^ (srow & 3) ^ ((srow >> 2) & 3);
    const unsigned short* srcA = A + (size_t)(m0 + srow) * D_N + sslot * 8;
    const int crow0 = crow_tab[n0 + srow];
    const int crow1 = crow_tab[n0 + srow + 64];
    const unsigned short* srcB0 = B + (size_t)crow0 * D_N + sslot * 8;
    const unsigned short* srcB1 = B + (size_t)crow1 * D_N + sslot * 8;
    const int ldst = tid * 16;
    const int rswz = (fk ^ (fr & 3) ^ ((fr >> 2) & 3)) << 4;

    f32x4 acc[4][4];
    #pragma unroll
    for (int m = 0; m < 4; ++m)
        #pragma unroll
        for (int n = 0; n < 4; ++n) acc[m][n] = (f32x4){0.f, 0.f, 0.f, 0.f};

    #define STAGE(t, buf)                                                              \
        {                                                                              \
            gload_lds16(srcA + (t) * BK, (char*)AsBuf[buf] + ldst);                    \
            gload_lds16(srcA + (size_t)64 * D_N + (t) * BK,                            \
                        (char*)AsBuf[buf] + 4096 + ldst);                              \
            gload_lds16(srcB0 + (t) * BK, (char*)BsBuf[buf] + ldst);                   \
            gload_lds16(srcB1 + (t) * BK, (char*)BsBuf[buf] + 4096 + ldst);            \
        }

    STAGE(0, 0)
    STAGE(1, 1)
    asm volatile("s_waitcnt vmcnt(4)" ::: "memory");
    __builtin_amdgcn_sched_barrier(0);
    __builtin_amdgcn_s_barrier();
    __builtin_amdgcn_sched_barrier(0);

    #pragma unroll
    for (int t = 0; t < KT; ++t) {
        const int cur = t & 1;
        const unsigned short* As = AsBuf[cur];
        const unsigned short* Bs = BsBuf[cur];
        bf16x8 af[4], bfr[4];
        #pragma unroll
        for (int m = 0; m < 4; ++m) {
            int rl = wr * 64 + m * 16 + fr;
            af[m] = *(const bf16x8*)((const char*)As + rl * 64 + rswz);
        }
        #pragma unroll
        for (int n = 0; n < 4; ++n) {
            int rl = wc * 64 + n * 16 + fr;
            bfr[n] = *(const bf16x8*)((const char*)Bs + rl * 64 + rswz);
        }
        #pragma unroll
        for (int m = 0; m < 4; ++m)
            #pragma unroll
            for (int n = 0; n < 4; ++n)
                acc[m][n] = __builtin_amdgcn_mfma_f32_16x16x32_bf16(af[m], bfr[n], acc[m][n], 0, 0, 0);
        __builtin_amdgcn_sched_barrier(0);
        __builtin_amdgcn_s_barrier();
        __builtin_amdgcn_sched_barrier(0);
        if (t + 2 < KT) STAGE(t + 2, cur)
        if (t + 1 < KT) {
            if (t + 2 < KT) {
                asm volatile("s_waitcnt vmcnt(4)" ::: "memory");
            } else {
                asm volatile("s_waitcnt vmcnt(0)" ::: "memory");
            }
            __builtin_amdgcn_sched_barrier(0);
            __builtin_amdgcn_s_barrier();
            __builtin_amdgcn_sched_barrier(0);
        }
    }
    #undef STAGE

    #pragma unroll
    for (int n = 0; n < 4; ++n) {
        int ccol = n0 + wc * 64 + n * 16 + fr;
        if (ccol < NV) {
            int cw = cw_tab[ccol];
            int c = cw >> 5, w = cw & 31;
            #pragma unroll
            for (int m = 0; m < 4; ++m) {
                #pragma unroll
                for (int j = 0; j < 4; ++j) {
                    int row = m0 + wr * 64 + m * 16 + fk * 4 + j;
                    int i = row / R_N, r = row - i * R_N;
                    attn[(((size_t)i * C_N + c) * R_N + r) * W_N + w] = f2bf(acc[m][n][j]);
                }
            }
        }
    }
}

// ---------------------------------------------------------------------------
// Kernel 2: score (R13/R18/R20 verified form — CG=8, one column/thread).
// ---------------------------------------------------------------------------
#define CG 8
#define SCL9 12.98425537f   // 9 * log2(e)

__global__ __launch_bounds__(192) void score_kernel(const unsigned short* __restrict__ attn,
                                                    const unsigned int* __restrict__ G2,
                                                    const float* __restrict__ capn,
                                                    const int* __restrict__ cap_lens,
                                                    float* __restrict__ scores) {
    __shared__ unsigned short stage[CG * R_N * W_N];
    __shared__ __align__(16) unsigned int gsh2[R_N * 20];
    __shared__ float scl_sh[CG * R_N];
    __shared__ float red[CG][W_N];
    __shared__ int len_sh[CG];
    const int i = blockIdx.x;
    const int c0 = blockIdx.y * CG;
    const int tid = threadIdx.x;

    if (tid < CG) len_sh[tid] = cap_lens[c0 + tid];
    const unsigned short* at = attn + ((size_t)i * C_N + c0) * R_N * W_N;
    for (int ch = tid; ch < CG * R_N * W_N / 8; ch += 192)
        *(u16x8*)&stage[ch * 8] = *(const u16x8*)(at + ch * 8);
    const unsigned int* gp = G2 + (size_t)i * (R_N * 20);
    if (tid < 180) ((uint4*)gsh2)[tid] = ((const uint4*)gp)[tid];
    __syncthreads();

    for (int row = tid; row < CG * R_N; row += 192) {
        int cl = row / R_N;
        int len = len_sh[cl];
        const unsigned short* rp = &stage[row * W_N];
        u16x8 p0 = *(const u16x8*)&rp[0];
        u16x8 p1 = *(const u16x8*)&rp[8];
        u16x8 p2 = *(const u16x8*)&rp[16];
        float ss = 0.f;
        #pragma unroll
        for (int q = 0; q < 8; ++q) {
            float x0 = bf2f(p0[q]); x0 = x0 > 0.f ? x0 : 0.1f * x0; x0 = (q      < len) ? x0 : 0.f;
            float x1 = bf2f(p1[q]); x1 = x1 > 0.f ? x1 : 0.1f * x1; x1 = (q + 8  < len) ? x1 : 0.f;
            float x2 = bf2f(p2[q]); x2 = x2 > 0.f ? x2 : 0.1f * x2; x2 = (q + 16 < len) ? x2 : 0.f;
            ss += x0 * x0 + x1 * x1 + x2 * x2;
        }
        scl_sh[row] = SCL9 / (sqrtf(ss) + 1e-8f);
    }
    __syncthreads();

    {
        const int cl = tid / W_N, w = tid - cl * W_N;
        const int len = len_sh[cl];
        const bool valid = w < len;
        const unsigned short* sb = &stage[cl * R_N * W_N];
        const float* sclp = &scl_sh[cl * R_N];
        f16x2 ep[18];
        float Z = 0.f, nu = 0.f;
        float e_prev = 0.f;
        #pragma unroll
        for (int r = 0; r < R_N; ++r) {
            float raw = bf2f(sb[r * W_N + w]);
            float x = raw > 0.f ? raw : 0.1f * raw;
            float l = valid ? x * sclp[r] : 0.f;
            float e = exp2f(l);
            Z += e;
            nu += e * raw;
            if (r & 1) ep[r >> 1] = pkf16(e_prev, e);
            else e_prev = e;
        }
        float wn = 0.f;
        #pragma unroll
        for (int r2 = 0; r2 < R_N; ++r2) {
            const unsigned int* grow = &gsh2[r2 * 20];
            uint4 q0 = *(const uint4*)(grow + 0);
            uint4 q1 = *(const uint4*)(grow + 4);
            uint4 q2 = *(const uint4*)(grow + 8);
            uint4 q3 = *(const uint4*)(grow + 12);
            uint2 q4 = *(const uint2*)(grow + 16);
            unsigned int gq[18] = {q0.x, q0.y, q0.z, q0.w, q1.x, q1.y, q1.z, q1.w,
                                   q2.x, q2.y, q2.z, q2.w, q3.x, q3.y, q3.z, q3.w,
                                   q4.x, q4.y};
            float t0 = 0.f, t1 = 0.f;
            #pragma unroll
            for (int p = 0; p < 18; ++p) {
                f16x2 g = __builtin_bit_cast(f16x2, gq[p]);
                if (p & 1) t1 = fdot2f(g, ep[p], t1);
                else       t0 = fdot2f(g, ep[p], t0);
            }
            wn += (t0 + t1) * (float)ep[r2 >> 1][r2 & 1];
        }
        float iZ = 1.f / Z;
        float cn = capn[(c0 + cl) * W_N + w];
        float den = fmaxf(cn * sqrtf(fmaxf(wn, 0.f)) * iZ, 1e-8f);
        red[cl][w] = valid ? (nu * iZ) / den * 6.0f : -3.4e38f;
    }
    __syncthreads();
    if (tid < CG) {
        float se = 0.f;
        #pragma unroll
        for (int w = 0; w < W_N; ++w) se += __expf(red[tid][w] - 6.0f);
        scores[(size_t)(c0 + tid) * I_N + i] = (__logf(se) + 6.0f) / 6.0f;
    }
}

// ---------------------------------------------------------------------------
// Kernel 3: final hinge loss. 1 block x 128 threads.
// ---------------------------------------------------------------------------
__global__ __launch_bounds__(128) void final_kernel(const float* __restrict__ scores,
                                                    float* __restrict__ out) {
    __shared__ float diag[C_N];
    __shared__ float red[C_N];
    const int t = threadIdx.x;
    diag[t] = scores[t * C_N + t];
    __syncthreads();
    const float di = diag[t];
    float cs = 0.f, cim = 0.f;
    for (int k = 0; k < C_N; ++k) {
        if (k == t) continue;
        float vs = 0.2f + scores[k * C_N + t] - di;
        float vi = 0.2f + scores[t * C_N + k] - di;
        cs = fmaxf(cs, vs);
        cim = fmaxf(cim, vi);
    }
    red[t] = cs + cim;
    __syncthreads();
    #pragma unroll
    for (int off = 64; off > 0; off >>= 1) {
        if (t < off) red[t] += red[t + off];
        __syncthreads();
    }
    if (t == 0) out[0] = red[0];
}

// ---------------------------------------------------------------------------
extern "C" void kernel_launch(void* const* d_in, const int* in_sizes, int n_in,
                              void* d_out, int out_size, void* d_ws, size_t ws_size,
                              hipStream_t stream) {
    (void)in_sizes; (void)n_in; (void)out_size; (void)ws_size;
    const float* images = (const float*)d_in[0];
    const float* captions = (const float*)d_in[1];
    const int* cap_lens = (const int*)d_in[2];
    float* out = (float*)d_out;

    char* wsb = (char*)d_ws;
    size_t off = 0;
    auto alloc = [&](size_t bytes) -> char* {
        char* p = wsb + off;
        off += (bytes + 255) & ~(size_t)255;
        return p;
    };
    unsigned short* imgbf = (unsigned short*)alloc((size_t)M_N * D_N * 2);
    unsigned short* capbf = (unsigned short*)alloc((size_t)N_N * D_N * 2);
    unsigned int* G2 = (unsigned int*)alloc((size_t)I_N * R_N * 20 * 4);
    float* capn = (float*)alloc((size_t)C_N * W_N * 4);
    float* scores = (float*)alloc((size_t)C_N * I_N * 4);
    int* NVp = (int*)alloc(256);
    int* crow_tab = (int*)alloc((size_t)N_N * 4);
    int* cw_tab = (int*)alloc((size_t)N_N * 4);
    unsigned short* attn = (unsigned short*)alloc((size_t)I_N * C_N * R_N * W_N * 2);

    prologue_kernel<<<2049, 256, 0, stream>>>(images, captions, cap_lens,
                                              imgbf, capbf, capn, G2,
                                              NVp, crow_tab, cw_tab);
    attn_gemm_kernel<<<GX * GY, 256, 0, stream>>>(imgbf, capbf, NVp, crow_tab, cw_tab, attn);
    score_kernel<<<dim3(I_N, C_N / CG), 192, 0, stream>>>(attn, G2, capn, cap_lens, scores);
    final_kernel<<<1, 128, 0, stream>>>(scores, out);
}